// Round 15
// baseline (247.034 us; speedup 1.0000x reference)
//
#include <hip/hip_runtime.h>

typedef __attribute__((ext_vector_type(4)))  float fx4;
typedef __attribute__((ext_vector_type(16))) float fx16;
typedef __attribute__((ext_vector_type(8)))  short bf8;
typedef __attribute__((ext_vector_type(4)))  unsigned int u32x4;

#define SCALE 0.17677669529663687f

__device__ __forceinline__ unsigned short f2bf(float f) {
  unsigned int u = __builtin_bit_cast(unsigned int, f);
  unsigned int r = (u + 0x7fffu + ((u >> 16) & 1u)) >> 16;
  return (unsigned short)r;
}
__device__ __forceinline__ float bf2f(unsigned short u) {
  unsigned int v = ((unsigned int)u) << 16;
  return __builtin_bit_cast(float, v);
}

// -------- K01: fused x->xT transpose + conv1x1 q/v (MFMA from LDS) --------
__global__ __launch_bounds__(256) void k01_qv(const float* __restrict__ x,
    const float* __restrict__ wq, const float* __restrict__ bq,
    const float* __restrict__ wv, const float* __restrict__ bv,
    unsigned short* __restrict__ xT, unsigned short* __restrict__ qT,
    unsigned short* __restrict__ vT) {
  int pt = blockIdx.x, b = blockIdx.y, t = threadIdx.x;
  __shared__ unsigned short tT[128 * 136];   // [pix][c], 68 KB, 272B stride (16B-aligned)
  const float* xb = x + (size_t)b * 524288 + pt * 128;
#pragma unroll
  for (int i = 0; i < 16; ++i) {
    int slot = t + i * 256;                  // 0..4095
    int c = slot >> 5, p4 = slot & 31;
    float4 v = *reinterpret_cast<const float4*>(xb + (size_t)c * 4096 + p4 * 4);
    unsigned short* q = &tT[(p4 * 4) * 136 + c];
    q[0] = f2bf(v.x); q[136] = f2bf(v.y); q[272] = f2bf(v.z); q[408] = f2bf(v.w);
  }
  __syncthreads();
  // write xT (bf16 NHWC)
  {
    int pix = t >> 1, hf = t & 1;
    unsigned short tmp[64];
#pragma unroll
    for (int j = 0; j < 64; ++j) tmp[j] = tT[pix * 136 + hf * 64 + j];
    unsigned short* dst = xT + ((size_t)b * 4096 + pt * 128 + pix) * 128 + hf * 64;
#pragma unroll
    for (int q = 0; q < 8; ++q)
      *reinterpret_cast<bf8*>(dst + q * 8) = *reinterpret_cast<bf8*>(tmp + q * 8);
  }
  int lane = t & 63, wave = t >> 6;
  int wm = wave >> 1, wn = wave & 1;
  int l31 = lane & 31, g2 = lane >> 5;
#pragma unroll
  for (int qv = 0; qv < 2; ++qv) {
    const float* W = qv ? wv : wq;
    const float* bias = qv ? bv : bq;
    unsigned short* out = qv ? vT : qT;
    fx16 acc[2][2] = {};
#pragma unroll
    for (int ks = 0; ks < 8; ++ks) {
      int kbase = ks * 16 + g2 * 8;
      bf8 a[2], bb[2];
#pragma unroll
      for (int mi = 0; mi < 2; ++mi) {
        int pix = (wm * 2 + mi) * 32 + l31;
        a[mi] = *reinterpret_cast<const bf8*>(&tT[pix * 136 + kbase]);
      }
#pragma unroll
      for (int ni = 0; ni < 2; ++ni) {
        int oc = (wn * 2 + ni) * 32 + l31;
        const float* wp = W + oc * 128 + kbase;
        float4 w0 = *reinterpret_cast<const float4*>(wp);
        float4 w1 = *reinterpret_cast<const float4*>(wp + 4);
        bf8 r;
        r[0]=(short)f2bf(w0.x); r[1]=(short)f2bf(w0.y); r[2]=(short)f2bf(w0.z); r[3]=(short)f2bf(w0.w);
        r[4]=(short)f2bf(w1.x); r[5]=(short)f2bf(w1.y); r[6]=(short)f2bf(w1.z); r[7]=(short)f2bf(w1.w);
        bb[ni] = r;
      }
#pragma unroll
      for (int mi = 0; mi < 2; ++mi)
#pragma unroll
        for (int ni = 0; ni < 2; ++ni)
          acc[mi][ni] = __builtin_amdgcn_mfma_f32_32x32x16_bf16(a[mi], bb[ni], acc[mi][ni], 0, 0, 0);
    }
#pragma unroll
    for (int ni = 0; ni < 2; ++ni) {
      int oc = (wn * 2 + ni) * 32 + l31;
      float bsv = bias[oc];
#pragma unroll
      for (int mi = 0; mi < 2; ++mi) {
#pragma unroll
        for (int r = 0; r < 16; ++r) {
          int row = (r & 3) + 8 * (r >> 2) + 4 * g2;
          int pix = pt * 128 + (wm * 2 + mi) * 32 + row;
          out[((size_t)b * 4096 + pix) * 128 + oc] = f2bf(acc[mi][ni][r] + bsv);
        }
      }
    }
  }
}

// -- K2: depthwise 5x5 -> lepe bf16 ONLY (16 strips of 4 rows) --
__global__ __launch_bounds__(256) void k2_lepe(const unsigned short* __restrict__ vT,
    const float* __restrict__ wl5, const float* __restrict__ bl,
    unsigned short* __restrict__ lepe) {
  int strip = blockIdx.x, hd = blockIdx.y, b = blockIdx.z;
  int t = threadIdx.x;
  __shared__ unsigned short tile[8 * 64 * 34];  // [row 8][w 64][c 32+pad2]
  int h0 = strip * 4;
#pragma unroll
  for (int i = 0; i < 8; ++i) {
    int slot = t + i * 256;                 // 0..2047
    int r = slot >> 8;                      // 0..7
    int rem = slot & 255;
    int w = rem >> 2, cc = rem & 3;
    int h = h0 - 2 + r;
    unsigned short vv[8];
    if (h >= 0 && h < 64) {
      *reinterpret_cast<bf8*>(vv) = *reinterpret_cast<const bf8*>(
          vT + ((size_t)b * 4096 + h * 64 + w) * 128 + hd * 32 + cc * 8);
    } else {
#pragma unroll
      for (int j = 0; j < 8; ++j) vv[j] = 0;
    }
    unsigned int* dst = reinterpret_cast<unsigned int*>(&tile[(r * 64 + w) * 34 + cc * 8]);
#pragma unroll
    for (int j = 0; j < 4; ++j)
      dst[j] = ((unsigned int)vv[2 * j + 1] << 16) | (unsigned int)vv[2 * j];
  }
  __syncthreads();
  int c2 = t & 15, w16 = t >> 4;
  int c = c2 * 2;
  float wt0[25], wt1[25];
#pragma unroll
  for (int i = 0; i < 25; ++i) {
    wt0[i] = wl5[(hd * 32 + c) * 25 + i];
    wt1[i] = wl5[(hd * 32 + c + 1) * 25 + i];
  }
  float b0 = bl[hd * 32 + c], b1 = bl[hd * 32 + c + 1];
  for (int hh = 0; hh < 4; ++hh) {
    for (int wi = 0; wi < 4; ++wi) {
      int w = w16 * 4 + wi;
      float a0 = b0, a1 = b1;
#pragma unroll
      for (int dy = 0; dy < 5; ++dy) {
        int rr = hh + dy;
#pragma unroll
        for (int dx = 0; dx < 5; ++dx) {
          int wx = w + dx - 2;
          if (wx < 0 || wx >= 64) continue;
          unsigned int pr = *reinterpret_cast<const unsigned int*>(&tile[(rr * 64 + wx) * 34 + c]);
          float v0 = bf2f((unsigned short)(pr & 0xffffu));
          float v1 = bf2f((unsigned short)(pr >> 16));
          a0 += v0 * wt0[dy * 5 + dx];
          a1 += v1 * wt1[dy * 5 + dx];
        }
      }
      size_t po = ((size_t)b * 4096 + (h0 + hh) * 64 + w) * 128 + hd * 32 + c;
      unsigned int lp = (unsigned int)f2bf(a0) | ((unsigned int)f2bf(a1) << 16);
      *reinterpret_cast<unsigned int*>(&lepe[po]) = lp;
    }
  }
}

// ---------------- K3: fused attention per (window, head) ----------------
// R14 + Q/lepe fragment prefetch: pass-0 qx/lx hoisted to prologue; pass-N+1
// qx/lx issued during pass N (same fence as the ai prefetch). Removes the two
// dependent scattered loads from each pass's serial head.
__global__ __launch_bounds__(256, 4) void k3_attn(
    const unsigned short* __restrict__ kT, const unsigned short* __restrict__ qS,
    const unsigned short* __restrict__ vT, const unsigned short* __restrict__ lepe,
    const float* __restrict__ ai, const float* __restrict__ temp,
    float* __restrict__ attn, unsigned short* __restrict__ out_win) {
  int w = blockIdx.x;           // window 0..255
  int hd = blockIdx.y;          // head 0..3
  int b = w >> 4, ww = w & 15;
  int t = threadIdx.x, lane = t & 63, wave = t >> 6;
  int l15 = lane & 15, g = (lane >> 4) & 3;
  __shared__ unsigned short Kf[16 * 4 * 16 * 8];     // 16 KB [nt][g][l15][j]
  __shared__ unsigned short Vf[16 * 4 * 16 * 8];     // 16 KB [(ks,dblk)][g][l15][j]
  __shared__ float Stg[4 * 512];                     //  8 KB per-wave store stage

  const size_t aBase = ((size_t)w * 4 + hd) * 65536;
  const float* aiB = ai + aBase;
  float* atB = attn + aBase;
  unsigned short* owB = out_win + ((size_t)w * 4 + hd) * 8192;

  // ---- prologue: issue pass-0 ai batch + pass-0 q/lepe frags BEFORE staging
  fx4 av[8];
  bf8 qx, lx;
  {
    int qrow0 = wave * 16 + l15;
    const fx4* aiRow0 = reinterpret_cast<const fx4*>(aiB + (size_t)qrow0 * 256 + g * 4);
#pragma unroll
    for (int nt = 0; nt < 8; ++nt) av[nt] = aiRow0[nt * 4];
    int pix = (qrow0 >> 2) * 64 + ww * 4 + (qrow0 & 3);
    size_t off = ((size_t)b * 4096 + pix) * 128 + hd * 32 + g * 8;
    qx = *reinterpret_cast<const bf8*>(qS + off);
    lx = *reinterpret_cast<const bf8*>(lepe + off);
  }
  asm volatile("" ::: "memory");   // keep the batch issued here

  // ---- stage K = x + lepe (fragment-major): thread t = window row t ----
  {
    int row = t;
    int pix = (row >> 2) * 64 + ww * 4 + (row & 3);
    size_t off = ((size_t)b * 4096 + pix) * 128 + hd * 32;
    const unsigned short* src = kT + off;
    const unsigned short* lsrc = lepe + off;
    int nt = row >> 4, sl = row & 15;
#pragma unroll
    for (int gg = 0; gg < 4; ++gg) {
      bf8 kx = *reinterpret_cast<const bf8*>(src + gg * 8);
      bf8 lk = *reinterpret_cast<const bf8*>(lsrc + gg * 8);
      bf8 r;
#pragma unroll
      for (int j = 0; j < 8; ++j)
        r[j] = (short)f2bf(bf2f((unsigned short)kx[j]) + bf2f((unsigned short)lk[j]));
      *reinterpret_cast<bf8*>(&Kf[((nt * 4 + gg) * 16 + sl) * 8]) = r;
    }
  }
  // ---- stage V (fragment-major transpose): thread t = window row t ----
  {
    int row = t;
    int pix = (row >> 2) * 64 + ww * 4 + (row & 3);
    const unsigned short* src = vT + ((size_t)b * 4096 + pix) * 128 + hd * 32;
    unsigned short vv[32];
#pragma unroll
    for (int q = 0; q < 4; ++q)
      *reinterpret_cast<bf8*>(vv + q * 8) = *reinterpret_cast<const bf8*>(src + q * 8);
    int ks = row >> 5, gg = (row >> 3) & 3, j = row & 7;
#pragma unroll
    for (int d = 0; d < 32; ++d)
      Vf[(((ks * 2 + (d >> 4)) * 4 + gg) * 16 + (d & 15)) * 8 + j] = vv[d];
  }
  __syncthreads();
  float tHd = temp[hd];

  int srcA = l15 + ((lane & 16) << 1);   // l15 + 32*(g&1)
  int srcB = srcA + 16;
  bool ghi = (lane >= 32);               // g >> 1
  float* Sw = Stg + wave * 512;          // [16 rows][32 dw]

  for (int pass = 0; pass < 4; ++pass) {
    int qbase = (pass * 4 + wave) * 16;
    int qrow = qbase + l15;
    const fx4* aiRow = reinterpret_cast<const fx4*>(aiB + (size_t)qrow * 256 + g * 4);

    // Q fragment from prefetched qx/lx
    bf8 qf;
#pragma unroll
    for (int j = 0; j < 8; ++j)
      qf[j] = (short)f2bf((bf2f((unsigned short)qx[j]) + bf2f((unsigned short)lx[j])) * SCALE);

    // S^T tiles: lane holds S[q=qrow][k=16nt+4g+r]
    fx4 acc[16];
#pragma unroll
    for (int nt = 0; nt < 16; ++nt) {
      bf8 kfr = *reinterpret_cast<const bf8*>(&Kf[((nt * 4 + g) * 16 + l15) * 8]);
      fx4 z; z[0] = 0.f; z[1] = 0.f; z[2] = 0.f; z[3] = 0.f;
      acc[nt] = __builtin_amdgcn_mfma_f32_16x16x32_bf16(kfr, qf, z, 0, 0, 0);
    }

    // softmax: 4-way ILP max tree, 2 shuffles across the g-quad
    float m0 = fmaxf(acc[0][0], acc[0][1]), m1 = fmaxf(acc[0][2], acc[0][3]);
    float m2 = fmaxf(acc[1][0], acc[1][1]), m3 = fmaxf(acc[1][2], acc[1][3]);
#pragma unroll
    for (int nt = 2; nt < 16; nt += 2) {
      m0 = fmaxf(m0, fmaxf(acc[nt][0], acc[nt][1]));
      m1 = fmaxf(m1, fmaxf(acc[nt][2], acc[nt][3]));
      m2 = fmaxf(m2, fmaxf(acc[nt + 1][0], acc[nt + 1][1]));
      m3 = fmaxf(m3, fmaxf(acc[nt + 1][2], acc[nt + 1][3]));
    }
    float m = fmaxf(fmaxf(m0, m1), fmaxf(m2, m3));
    m = fmaxf(m, __shfl_xor(m, 16));
    m = fmaxf(m, __shfl_xor(m, 32));

    float s0 = 0.f, s1 = 0.f, s2 = 0.f, s3 = 0.f;
#pragma unroll
    for (int nt = 0; nt < 16; ++nt) {
      float p0 = __expf(acc[nt][0] - m);
      float p1 = __expf(acc[nt][1] - m);
      float p2 = __expf(acc[nt][2] - m);
      float p3 = __expf(acc[nt][3] - m);
      acc[nt][0] = p0; acc[nt][1] = p1; acc[nt][2] = p2; acc[nt][3] = p3;
      s0 += p0; s1 += p1; s2 += p2; s3 += p3;
    }
    float s = (s0 + s1) + (s2 + s3);
    s += __shfl_xor(s, 16);
    s += __shfl_xor(s, 32);
    float inv = 1.0f / s;

    // issue second-half ai batch; latency hides under fold of first half
    fx4 av2[8];
#pragma unroll
    for (int nt = 0; nt < 8; ++nt) av2[nt] = aiRow[(8 + nt) * 4];
    asm volatile("" ::: "memory");

    // fold in nt-pairs: attn = p*inv + tHd*ai; stage pair to LDS, flush as
    // full 128B lines via NONTEMPORAL stores (no allocate / no RMW).
    unsigned int pp0[16], pp1[16];
#pragma unroll
    for (int p = 0; p < 8; ++p) {
#pragma unroll
      for (int u = 0; u < 2; ++u) {
        int nt = 2 * p + u;
        fx4 a4 = (nt < 8) ? av[nt] : av2[nt - 8];
        fx4 sv;
        sv[0] = acc[nt][0] * inv + tHd * a4[0];
        sv[1] = acc[nt][1] * inv + tHd * a4[1];
        sv[2] = acc[nt][2] * inv + tHd * a4[2];
        sv[3] = acc[nt][3] * inv + tHd * a4[3];
        int pc = (g + 4 * u) ^ (l15 & 7);
        *reinterpret_cast<fx4*>(&Sw[l15 * 32 + pc * 4]) = sv;
        pp0[nt] = (unsigned int)f2bf(sv[0]) | ((unsigned int)f2bf(sv[1]) << 16);
        pp1[nt] = (unsigned int)f2bf(sv[2]) | ((unsigned int)f2bf(sv[3]) << 16);
      }
#pragma unroll
      for (int i = 0; i < 2; ++i) {
        int r = (lane >> 3) + 8 * i;
        int cf = lane & 7;
        int pc = cf ^ (r & 7);
        fx4 v = *reinterpret_cast<const fx4*>(&Sw[r * 32 + pc * 4]);
        __builtin_nontemporal_store(v,
            reinterpret_cast<fx4*>(atB + (size_t)(qbase + r) * 256 + p * 32 + cf * 4));
      }
    }

    // prefetch next pass's first-half ai + q/lepe frags
    if (pass < 3) {
      int qrowN = ((pass + 1) * 4 + wave) * 16 + l15;
      const fx4* aiRowN = reinterpret_cast<const fx4*>(aiB + (size_t)qrowN * 256 + g * 4);
#pragma unroll
      for (int nt = 0; nt < 8; ++nt) av[nt] = aiRowN[nt * 4];
      int pixN = (qrowN >> 2) * 64 + ww * 4 + (qrowN & 3);
      size_t offN = ((size_t)b * 4096 + pixN) * 128 + hd * 32 + g * 8;
      qx = *reinterpret_cast<const bf8*>(qS + offN);
      lx = *reinterpret_cast<const bf8*>(lepe + offN);
      asm volatile("" ::: "memory");
    }

    // PV as out^T = V^T @ P^T ; B-frag via 8 shuffles + 4 selects per chunk
    fx4 oT[2];
    oT[0][0]=0.f;oT[0][1]=0.f;oT[0][2]=0.f;oT[0][3]=0.f;
    oT[1][0]=0.f;oT[1][1]=0.f;oT[1][2]=0.f;oT[1][3]=0.f;
#pragma unroll
    for (int c = 0; c < 8; ++c) {
      int n0 = 2 * c, n1 = 2 * c + 1;
      unsigned int x0 = (unsigned int)__shfl((int)pp0[n0], srcA);
      unsigned int y0 = (unsigned int)__shfl((int)pp0[n1], srcA);
      unsigned int x1 = (unsigned int)__shfl((int)pp1[n0], srcA);
      unsigned int y1 = (unsigned int)__shfl((int)pp1[n1], srcA);
      unsigned int x2 = (unsigned int)__shfl((int)pp0[n0], srcB);
      unsigned int y2 = (unsigned int)__shfl((int)pp0[n1], srcB);
      unsigned int x3 = (unsigned int)__shfl((int)pp1[n0], srcB);
      unsigned int y3 = (unsigned int)__shfl((int)pp1[n1], srcB);
      u32x4 bw;
      bw[0] = ghi ? y0 : x0;
      bw[1] = ghi ? y1 : x1;
      bw[2] = ghi ? y2 : x2;
      bw[3] = ghi ? y3 : x3;
      bf8 pf = __builtin_bit_cast(bf8, bw);
#pragma unroll
      for (int dblk = 0; dblk < 2; ++dblk) {
        bf8 vf = *reinterpret_cast<const bf8*>(&Vf[(((c * 2 + dblk) * 4 + g) * 16 + l15) * 8]);
        oT[dblk] = __builtin_amdgcn_mfma_f32_16x16x32_bf16(vf, pf, oT[dblk], 0, 0, 0);
      }
    }
    // out^T lane: q = qbase+l15, d = dblk*16 + g*4 + r -> bf16 8B stores
#pragma unroll
    for (int dblk = 0; dblk < 2; ++dblk) {
      unsigned int w0 = (unsigned int)f2bf(oT[dblk][0]) | ((unsigned int)f2bf(oT[dblk][1]) << 16);
      unsigned int w1 = (unsigned int)f2bf(oT[dblk][2]) | ((unsigned int)f2bf(oT[dblk][3]) << 16);
      uint2 st; st.x = w0; st.y = w1;
      *reinterpret_cast<uint2*>(&owB[(size_t)qrow * 32 + dblk * 16 + g * 4]) = st;
    }
  }
}

// ---------------- K4: out0 = un-window(ow bf16) + lepe(bf16) ----------------
// bf16 LDS tiles (34 KB -> 4 blocks/CU, one dispatch round).
__global__ __launch_bounds__(256) void k4_out(const unsigned short* __restrict__ out_win,
    const unsigned short* __restrict__ lepe, float* __restrict__ out0) {
  int h = blockIdx.x, b = blockIdx.y, t = threadIdx.x;
  __shared__ unsigned short winb[16 * 552];   // strides: ww 552, wl 136, hd 34 (u32-aligned)
  __shared__ unsigned short lep[64 * 130];
#pragma unroll
  for (int i = 0; i < 4; ++i) {
    int slot = t + i * 256;          // 0..1023 bf16x8 chunks
    int ww = slot >> 6, rem = slot & 63;
    int hdq = rem >> 4, rem2 = rem & 15;
    int wl = rem2 >> 2, dq = rem2 & 3;
    bf8 v = *reinterpret_cast<const bf8*>(
        out_win + (((size_t)(b * 16 + ww) * 4 + hdq) * 256 + h * 4 + wl) * 32 + dq * 8);
    u32x4 u = __builtin_bit_cast(u32x4, v);
    unsigned int* p = reinterpret_cast<unsigned int*>(&winb[ww * 552 + wl * 136 + hdq * 34 + dq * 8]);
    p[0] = u[0]; p[1] = u[1]; p[2] = u[2]; p[3] = u[3];
  }
#pragma unroll
  for (int i = 0; i < 4; ++i) {
    int slot = t + i * 256;          // 0..1023 bf16x8 slots
    int w = slot >> 4, cq = slot & 15;
    bf8 lv = *reinterpret_cast<const bf8*>(
        lepe + ((size_t)b * 4096 + h * 64 + w) * 128 + cq * 8);
    u32x4 u = __builtin_bit_cast(u32x4, lv);
    unsigned int* p = reinterpret_cast<unsigned int*>(&lep[w * 130 + cq * 8]);
    p[0] = u[0]; p[1] = u[1]; p[2] = u[2]; p[3] = u[3];
  }
  __syncthreads();
  int w = t & 63, cg = t >> 6;
#pragma unroll
  for (int ci = 0; ci < 32; ++ci) {
    int c = cg * 32 + ci;
    float val = bf2f(winb[(w >> 2) * 552 + (w & 3) * 136 + (c >> 5) * 34 + (c & 31)])
              + bf2f(lep[w * 130 + c]);
    out0[((size_t)(b * 128 + c) * 64 + h) * 64 + w] = val;
  }
}

extern "C" void kernel_launch(void* const* d_in, const int* in_sizes, int n_in,
                              void* d_out, int out_size, void* d_ws, size_t ws_size,
                              hipStream_t stream) {
  const float* x    = (const float*)d_in[0];
  const float* ai   = (const float*)d_in[1];
  const float* wq   = (const float*)d_in[2];
  const float* bq   = (const float*)d_in[3];
  const float* wv   = (const float*)d_in[4];
  const float* bv   = (const float*)d_in[5];
  const float* wl5  = (const float*)d_in[6];
  const float* bl   = (const float*)d_in[7];
  const float* temp = (const float*)d_in[8];
  float* out0 = (float*)d_out;
  float* attn = out0 + 8388608;

  char* ws = (char*)d_ws;
  unsigned short* xT = (unsigned short*)(ws);                 // 16 MB bf16 (raw x)
  unsigned short* qT = (unsigned short*)(ws + 16777216);      // 16 MB bf16 (raw q_map)
  unsigned short* vT = (unsigned short*)(ws + 33554432);      // 16 MB bf16
  unsigned short* lepe = (unsigned short*)(ws + 50331648);    // 16 MB bf16 NHWC
  unsigned short* ow = (unsigned short*)(ws + 83886080);      // 16 MB bf16 windowed

  k01_qv <<<dim3(32, 16),    256, 0, stream>>>(x, wq, bq, wv, bv, xT, qT, vT);
  k2_lepe<<<dim3(16, 4, 16), 256, 0, stream>>>(vT, wl5, bl, lepe);
  k3_attn<<<dim3(256, 4),    256, 0, stream>>>(xT, qT, vT, lepe, ai, temp, attn, ow);
  k4_out <<<dim3(64, 16),    256, 0, stream>>>(ow, lepe, out0);
}

// Round 16
// 234.379 us; speedup vs baseline: 1.0540x; 1.0540x over previous
//
#include <hip/hip_runtime.h>

typedef __attribute__((ext_vector_type(4)))  float fx4;
typedef __attribute__((ext_vector_type(16))) float fx16;
typedef __attribute__((ext_vector_type(8)))  short bf8;
typedef __attribute__((ext_vector_type(4)))  unsigned int u32x4;

#define SCALE 0.17677669529663687f

__device__ __forceinline__ unsigned short f2bf(float f) {
  unsigned int u = __builtin_bit_cast(unsigned int, f);
  unsigned int r = (u + 0x7fffu + ((u >> 16) & 1u)) >> 16;
  return (unsigned short)r;
}
__device__ __forceinline__ float bf2f(unsigned short u) {
  unsigned int v = ((unsigned int)u) << 16;
  return __builtin_bit_cast(float, v);
}

// -------- K01: fused x->xT transpose + conv1x1 q/v (MFMA from LDS) --------
__global__ __launch_bounds__(256) void k01_qv(const float* __restrict__ x,
    const float* __restrict__ wq, const float* __restrict__ bq,
    const float* __restrict__ wv, const float* __restrict__ bv,
    unsigned short* __restrict__ xT, unsigned short* __restrict__ qT,
    unsigned short* __restrict__ vT) {
  int pt = blockIdx.x, b = blockIdx.y, t = threadIdx.x;
  __shared__ unsigned short tT[128 * 136];   // [pix][c], 68 KB, 272B stride (16B-aligned)
  const float* xb = x + (size_t)b * 524288 + pt * 128;
#pragma unroll
  for (int i = 0; i < 16; ++i) {
    int slot = t + i * 256;                  // 0..4095
    int c = slot >> 5, p4 = slot & 31;
    float4 v = *reinterpret_cast<const float4*>(xb + (size_t)c * 4096 + p4 * 4);
    unsigned short* q = &tT[(p4 * 4) * 136 + c];
    q[0] = f2bf(v.x); q[136] = f2bf(v.y); q[272] = f2bf(v.z); q[408] = f2bf(v.w);
  }
  __syncthreads();
  // write xT (bf16 NHWC)
  {
    int pix = t >> 1, hf = t & 1;
    unsigned short tmp[64];
#pragma unroll
    for (int j = 0; j < 64; ++j) tmp[j] = tT[pix * 136 + hf * 64 + j];
    unsigned short* dst = xT + ((size_t)b * 4096 + pt * 128 + pix) * 128 + hf * 64;
#pragma unroll
    for (int q = 0; q < 8; ++q)
      *reinterpret_cast<bf8*>(dst + q * 8) = *reinterpret_cast<bf8*>(tmp + q * 8);
  }
  int lane = t & 63, wave = t >> 6;
  int wm = wave >> 1, wn = wave & 1;
  int l31 = lane & 31, g2 = lane >> 5;
#pragma unroll
  for (int qv = 0; qv < 2; ++qv) {
    const float* W = qv ? wv : wq;
    const float* bias = qv ? bv : bq;
    unsigned short* out = qv ? vT : qT;
    fx16 acc[2][2] = {};
#pragma unroll
    for (int ks = 0; ks < 8; ++ks) {
      int kbase = ks * 16 + g2 * 8;
      bf8 a[2], bb[2];
#pragma unroll
      for (int mi = 0; mi < 2; ++mi) {
        int pix = (wm * 2 + mi) * 32 + l31;
        a[mi] = *reinterpret_cast<const bf8*>(&tT[pix * 136 + kbase]);
      }
#pragma unroll
      for (int ni = 0; ni < 2; ++ni) {
        int oc = (wn * 2 + ni) * 32 + l31;
        const float* wp = W + oc * 128 + kbase;
        float4 w0 = *reinterpret_cast<const float4*>(wp);
        float4 w1 = *reinterpret_cast<const float4*>(wp + 4);
        bf8 r;
        r[0]=(short)f2bf(w0.x); r[1]=(short)f2bf(w0.y); r[2]=(short)f2bf(w0.z); r[3]=(short)f2bf(w0.w);
        r[4]=(short)f2bf(w1.x); r[5]=(short)f2bf(w1.y); r[6]=(short)f2bf(w1.z); r[7]=(short)f2bf(w1.w);
        bb[ni] = r;
      }
#pragma unroll
      for (int mi = 0; mi < 2; ++mi)
#pragma unroll
        for (int ni = 0; ni < 2; ++ni)
          acc[mi][ni] = __builtin_amdgcn_mfma_f32_32x32x16_bf16(a[mi], bb[ni], acc[mi][ni], 0, 0, 0);
    }
#pragma unroll
    for (int ni = 0; ni < 2; ++ni) {
      int oc = (wn * 2 + ni) * 32 + l31;
      float bsv = bias[oc];
#pragma unroll
      for (int mi = 0; mi < 2; ++mi) {
#pragma unroll
        for (int r = 0; r < 16; ++r) {
          int row = (r & 3) + 8 * (r >> 2) + 4 * g2;
          int pix = pt * 128 + (wm * 2 + mi) * 32 + row;
          out[((size_t)b * 4096 + pix) * 128 + oc] = f2bf(acc[mi][ni][r] + bsv);
        }
      }
    }
  }
}

// -- K2: depthwise 5x5 -> lepe bf16 ONLY (16 strips of 4 rows) --
__global__ __launch_bounds__(256) void k2_lepe(const unsigned short* __restrict__ vT,
    const float* __restrict__ wl5, const float* __restrict__ bl,
    unsigned short* __restrict__ lepe) {
  int strip = blockIdx.x, hd = blockIdx.y, b = blockIdx.z;
  int t = threadIdx.x;
  __shared__ unsigned short tile[8 * 64 * 34];  // [row 8][w 64][c 32+pad2]
  int h0 = strip * 4;
#pragma unroll
  for (int i = 0; i < 8; ++i) {
    int slot = t + i * 256;                 // 0..2047
    int r = slot >> 8;                      // 0..7
    int rem = slot & 255;
    int w = rem >> 2, cc = rem & 3;
    int h = h0 - 2 + r;
    unsigned short vv[8];
    if (h >= 0 && h < 64) {
      *reinterpret_cast<bf8*>(vv) = *reinterpret_cast<const bf8*>(
          vT + ((size_t)b * 4096 + h * 64 + w) * 128 + hd * 32 + cc * 8);
    } else {
#pragma unroll
      for (int j = 0; j < 8; ++j) vv[j] = 0;
    }
    unsigned int* dst = reinterpret_cast<unsigned int*>(&tile[(r * 64 + w) * 34 + cc * 8]);
#pragma unroll
    for (int j = 0; j < 4; ++j)
      dst[j] = ((unsigned int)vv[2 * j + 1] << 16) | (unsigned int)vv[2 * j];
  }
  __syncthreads();
  int c2 = t & 15, w16 = t >> 4;
  int c = c2 * 2;
  float wt0[25], wt1[25];
#pragma unroll
  for (int i = 0; i < 25; ++i) {
    wt0[i] = wl5[(hd * 32 + c) * 25 + i];
    wt1[i] = wl5[(hd * 32 + c + 1) * 25 + i];
  }
  float b0 = bl[hd * 32 + c], b1 = bl[hd * 32 + c + 1];
  for (int hh = 0; hh < 4; ++hh) {
    for (int wi = 0; wi < 4; ++wi) {
      int w = w16 * 4 + wi;
      float a0 = b0, a1 = b1;
#pragma unroll
      for (int dy = 0; dy < 5; ++dy) {
        int rr = hh + dy;
#pragma unroll
        for (int dx = 0; dx < 5; ++dx) {
          int wx = w + dx - 2;
          if (wx < 0 || wx >= 64) continue;
          unsigned int pr = *reinterpret_cast<const unsigned int*>(&tile[(rr * 64 + wx) * 34 + c]);
          float v0 = bf2f((unsigned short)(pr & 0xffffu));
          float v1 = bf2f((unsigned short)(pr >> 16));
          a0 += v0 * wt0[dy * 5 + dx];
          a1 += v1 * wt1[dy * 5 + dx];
        }
      }
      size_t po = ((size_t)b * 4096 + (h0 + hh) * 64 + w) * 128 + hd * 32 + c;
      unsigned int lp = (unsigned int)f2bf(a0) | ((unsigned int)f2bf(a1) << 16);
      *reinterpret_cast<unsigned int*>(&lepe[po]) = lp;
    }
  }
}

// ---------------- K3: fused attention per (window, head) ----------------
// R14 verbatim (best measured k3): lepe folded at staging; pass-head Q load;
// two forced ai batches; staged full-128B-line NONTEMPORAL attn flush;
// swapped QK^T; in-register P^T PV.
__global__ __launch_bounds__(256, 4) void k3_attn(
    const unsigned short* __restrict__ kT, const unsigned short* __restrict__ qS,
    const unsigned short* __restrict__ vT, const unsigned short* __restrict__ lepe,
    const float* __restrict__ ai, const float* __restrict__ temp,
    float* __restrict__ attn, unsigned short* __restrict__ out_win) {
  int w = blockIdx.x;           // window 0..255
  int hd = blockIdx.y;          // head 0..3
  int b = w >> 4, ww = w & 15;
  int t = threadIdx.x, lane = t & 63, wave = t >> 6;
  int l15 = lane & 15, g = (lane >> 4) & 3;
  __shared__ unsigned short Kf[16 * 4 * 16 * 8];     // 16 KB [nt][g][l15][j]
  __shared__ unsigned short Vf[16 * 4 * 16 * 8];     // 16 KB [(ks,dblk)][g][l15][j]
  __shared__ float Stg[4 * 512];                     //  8 KB per-wave store stage

  const size_t aBase = ((size_t)w * 4 + hd) * 65536;
  const float* aiB = ai + aBase;
  float* atB = attn + aBase;
  unsigned short* owB = out_win + ((size_t)w * 4 + hd) * 8192;

  // ---- prologue: issue pass-0 first-half ai batch BEFORE staging ----
  fx4 av[8];
  {
    int qrow0 = wave * 16 + l15;
    const fx4* aiRow0 = reinterpret_cast<const fx4*>(aiB + (size_t)qrow0 * 256 + g * 4);
#pragma unroll
    for (int nt = 0; nt < 8; ++nt) av[nt] = aiRow0[nt * 4];
  }
  asm volatile("" ::: "memory");   // keep the batch issued here

  // ---- stage K = x + lepe (fragment-major): thread t = window row t ----
  {
    int row = t;
    int pix = (row >> 2) * 64 + ww * 4 + (row & 3);
    size_t off = ((size_t)b * 4096 + pix) * 128 + hd * 32;
    const unsigned short* src = kT + off;
    const unsigned short* lsrc = lepe + off;
    int nt = row >> 4, sl = row & 15;
#pragma unroll
    for (int gg = 0; gg < 4; ++gg) {
      bf8 kx = *reinterpret_cast<const bf8*>(src + gg * 8);
      bf8 lk = *reinterpret_cast<const bf8*>(lsrc + gg * 8);
      bf8 r;
#pragma unroll
      for (int j = 0; j < 8; ++j)
        r[j] = (short)f2bf(bf2f((unsigned short)kx[j]) + bf2f((unsigned short)lk[j]));
      *reinterpret_cast<bf8*>(&Kf[((nt * 4 + gg) * 16 + sl) * 8]) = r;
    }
  }
  // ---- stage V (fragment-major transpose): thread t = window row t ----
  {
    int row = t;
    int pix = (row >> 2) * 64 + ww * 4 + (row & 3);
    const unsigned short* src = vT + ((size_t)b * 4096 + pix) * 128 + hd * 32;
    unsigned short vv[32];
#pragma unroll
    for (int q = 0; q < 4; ++q)
      *reinterpret_cast<bf8*>(vv + q * 8) = *reinterpret_cast<const bf8*>(src + q * 8);
    int ks = row >> 5, gg = (row >> 3) & 3, j = row & 7;
#pragma unroll
    for (int d = 0; d < 32; ++d)
      Vf[(((ks * 2 + (d >> 4)) * 4 + gg) * 16 + (d & 15)) * 8 + j] = vv[d];
  }
  __syncthreads();
  float tHd = temp[hd];

  int srcA = l15 + ((lane & 16) << 1);   // l15 + 32*(g&1)
  int srcB = srcA + 16;
  bool ghi = (lane >= 32);               // g >> 1
  float* Sw = Stg + wave * 512;          // [16 rows][32 dw]

  for (int pass = 0; pass < 4; ++pass) {
    int qbase = (pass * 4 + wave) * 16;
    int qrow = qbase + l15;
    const fx4* aiRow = reinterpret_cast<const fx4*>(aiB + (size_t)qrow * 256 + g * 4);

    bf8 qf;
    {
      int pix = (qrow >> 2) * 64 + ww * 4 + (qrow & 3);
      size_t off = ((size_t)b * 4096 + pix) * 128 + hd * 32 + g * 8;
      bf8 qx = *reinterpret_cast<const bf8*>(qS + off);
      bf8 lx = *reinterpret_cast<const bf8*>(lepe + off);
#pragma unroll
      for (int j = 0; j < 8; ++j)
        qf[j] = (short)f2bf((bf2f((unsigned short)qx[j]) + bf2f((unsigned short)lx[j])) * SCALE);
    }

    // S^T tiles: lane holds S[q=qrow][k=16nt+4g+r]
    fx4 acc[16];
#pragma unroll
    for (int nt = 0; nt < 16; ++nt) {
      bf8 kfr = *reinterpret_cast<const bf8*>(&Kf[((nt * 4 + g) * 16 + l15) * 8]);
      fx4 z; z[0] = 0.f; z[1] = 0.f; z[2] = 0.f; z[3] = 0.f;
      acc[nt] = __builtin_amdgcn_mfma_f32_16x16x32_bf16(kfr, qf, z, 0, 0, 0);
    }

    // softmax: 4-way ILP max tree, 2 shuffles across the g-quad
    float m0 = fmaxf(acc[0][0], acc[0][1]), m1 = fmaxf(acc[0][2], acc[0][3]);
    float m2 = fmaxf(acc[1][0], acc[1][1]), m3 = fmaxf(acc[1][2], acc[1][3]);
#pragma unroll
    for (int nt = 2; nt < 16; nt += 2) {
      m0 = fmaxf(m0, fmaxf(acc[nt][0], acc[nt][1]));
      m1 = fmaxf(m1, fmaxf(acc[nt][2], acc[nt][3]));
      m2 = fmaxf(m2, fmaxf(acc[nt + 1][0], acc[nt + 1][1]));
      m3 = fmaxf(m3, fmaxf(acc[nt + 1][2], acc[nt + 1][3]));
    }
    float m = fmaxf(fmaxf(m0, m1), fmaxf(m2, m3));
    m = fmaxf(m, __shfl_xor(m, 16));
    m = fmaxf(m, __shfl_xor(m, 32));

    float s0 = 0.f, s1 = 0.f, s2 = 0.f, s3 = 0.f;
#pragma unroll
    for (int nt = 0; nt < 16; ++nt) {
      float p0 = __expf(acc[nt][0] - m);
      float p1 = __expf(acc[nt][1] - m);
      float p2 = __expf(acc[nt][2] - m);
      float p3 = __expf(acc[nt][3] - m);
      acc[nt][0] = p0; acc[nt][1] = p1; acc[nt][2] = p2; acc[nt][3] = p3;
      s0 += p0; s1 += p1; s2 += p2; s3 += p3;
    }
    float s = (s0 + s1) + (s2 + s3);
    s += __shfl_xor(s, 16);
    s += __shfl_xor(s, 32);
    float inv = 1.0f / s;

    // issue second-half ai batch; latency hides under fold of first half
    fx4 av2[8];
#pragma unroll
    for (int nt = 0; nt < 8; ++nt) av2[nt] = aiRow[(8 + nt) * 4];
    asm volatile("" ::: "memory");

    // fold in nt-pairs: attn = p*inv + tHd*ai; stage pair to LDS, flush as
    // full 128B lines via NONTEMPORAL stores (no allocate / no RMW).
    unsigned int pp0[16], pp1[16];
#pragma unroll
    for (int p = 0; p < 8; ++p) {
#pragma unroll
      for (int u = 0; u < 2; ++u) {
        int nt = 2 * p + u;
        fx4 a4 = (nt < 8) ? av[nt] : av2[nt - 8];
        fx4 sv;
        sv[0] = acc[nt][0] * inv + tHd * a4[0];
        sv[1] = acc[nt][1] * inv + tHd * a4[1];
        sv[2] = acc[nt][2] * inv + tHd * a4[2];
        sv[3] = acc[nt][3] * inv + tHd * a4[3];
        int pc = (g + 4 * u) ^ (l15 & 7);
        *reinterpret_cast<fx4*>(&Sw[l15 * 32 + pc * 4]) = sv;
        pp0[nt] = (unsigned int)f2bf(sv[0]) | ((unsigned int)f2bf(sv[1]) << 16);
        pp1[nt] = (unsigned int)f2bf(sv[2]) | ((unsigned int)f2bf(sv[3]) << 16);
      }
#pragma unroll
      for (int i = 0; i < 2; ++i) {
        int r = (lane >> 3) + 8 * i;
        int cf = lane & 7;
        int pc = cf ^ (r & 7);
        fx4 v = *reinterpret_cast<const fx4*>(&Sw[r * 32 + pc * 4]);
        __builtin_nontemporal_store(v,
            reinterpret_cast<fx4*>(atB + (size_t)(qbase + r) * 256 + p * 32 + cf * 4));
      }
    }

    // prefetch next pass's first-half ai; hides under PV + next QK + softmax
    if (pass < 3) {
      int qrowN = ((pass + 1) * 4 + wave) * 16 + l15;
      const fx4* aiRowN = reinterpret_cast<const fx4*>(aiB + (size_t)qrowN * 256 + g * 4);
#pragma unroll
      for (int nt = 0; nt < 8; ++nt) av[nt] = aiRowN[nt * 4];
      asm volatile("" ::: "memory");
    }

    // PV as out^T = V^T @ P^T ; B-frag via 8 shuffles + 4 selects per chunk
    fx4 oT[2];
    oT[0][0]=0.f;oT[0][1]=0.f;oT[0][2]=0.f;oT[0][3]=0.f;
    oT[1][0]=0.f;oT[1][1]=0.f;oT[1][2]=0.f;oT[1][3]=0.f;
#pragma unroll
    for (int c = 0; c < 8; ++c) {
      int n0 = 2 * c, n1 = 2 * c + 1;
      unsigned int x0 = (unsigned int)__shfl((int)pp0[n0], srcA);
      unsigned int y0 = (unsigned int)__shfl((int)pp0[n1], srcA);
      unsigned int x1 = (unsigned int)__shfl((int)pp1[n0], srcA);
      unsigned int y1 = (unsigned int)__shfl((int)pp1[n1], srcA);
      unsigned int x2 = (unsigned int)__shfl((int)pp0[n0], srcB);
      unsigned int y2 = (unsigned int)__shfl((int)pp0[n1], srcB);
      unsigned int x3 = (unsigned int)__shfl((int)pp1[n0], srcB);
      unsigned int y3 = (unsigned int)__shfl((int)pp1[n1], srcB);
      u32x4 bw;
      bw[0] = ghi ? y0 : x0;
      bw[1] = ghi ? y1 : x1;
      bw[2] = ghi ? y2 : x2;
      bw[3] = ghi ? y3 : x3;
      bf8 pf = __builtin_bit_cast(bf8, bw);
#pragma unroll
      for (int dblk = 0; dblk < 2; ++dblk) {
        bf8 vf = *reinterpret_cast<const bf8*>(&Vf[(((c * 2 + dblk) * 4 + g) * 16 + l15) * 8]);
        oT[dblk] = __builtin_amdgcn_mfma_f32_16x16x32_bf16(vf, pf, oT[dblk], 0, 0, 0);
      }
    }
    // out^T lane: q = qbase+l15, d = dblk*16 + g*4 + r -> bf16 8B stores
#pragma unroll
    for (int dblk = 0; dblk < 2; ++dblk) {
      unsigned int w0 = (unsigned int)f2bf(oT[dblk][0]) | ((unsigned int)f2bf(oT[dblk][1]) << 16);
      unsigned int w1 = (unsigned int)f2bf(oT[dblk][2]) | ((unsigned int)f2bf(oT[dblk][3]) << 16);
      uint2 st; st.x = w0; st.y = w1;
      *reinterpret_cast<uint2*>(&owB[(size_t)qrow * 32 + dblk * 16 + g * 4]) = st;
    }
  }
}

// ---------------- K4: out0 = un-window(ow bf16) + lepe(bf16) ----------------
// bf16 LDS tiles (34 KB -> 4 blocks/CU, one dispatch round).
__global__ __launch_bounds__(256) void k4_out(const unsigned short* __restrict__ out_win,
    const unsigned short* __restrict__ lepe, float* __restrict__ out0) {
  int h = blockIdx.x, b = blockIdx.y, t = threadIdx.x;
  __shared__ unsigned short winb[16 * 552];   // strides: ww 552, wl 136, hd 34 (u32-aligned)
  __shared__ unsigned short lep[64 * 130];
#pragma unroll
  for (int i = 0; i < 4; ++i) {
    int slot = t + i * 256;          // 0..1023 bf16x8 chunks
    int ww = slot >> 6, rem = slot & 63;
    int hdq = rem >> 4, rem2 = rem & 15;
    int wl = rem2 >> 2, dq = rem2 & 3;
    bf8 v = *reinterpret_cast<const bf8*>(
        out_win + (((size_t)(b * 16 + ww) * 4 + hdq) * 256 + h * 4 + wl) * 32 + dq * 8);
    u32x4 u = __builtin_bit_cast(u32x4, v);
    unsigned int* p = reinterpret_cast<unsigned int*>(&winb[ww * 552 + wl * 136 + hdq * 34 + dq * 8]);
    p[0] = u[0]; p[1] = u[1]; p[2] = u[2]; p[3] = u[3];
  }
#pragma unroll
  for (int i = 0; i < 4; ++i) {
    int slot = t + i * 256;          // 0..1023 bf16x8 slots
    int w = slot >> 4, cq = slot & 15;
    bf8 lv = *reinterpret_cast<const bf8*>(
        lepe + ((size_t)b * 4096 + h * 64 + w) * 128 + cq * 8);
    u32x4 u = __builtin_bit_cast(u32x4, lv);
    unsigned int* p = reinterpret_cast<unsigned int*>(&lep[w * 130 + cq * 8]);
    p[0] = u[0]; p[1] = u[1]; p[2] = u[2]; p[3] = u[3];
  }
  __syncthreads();
  int w = t & 63, cg = t >> 6;
#pragma unroll
  for (int ci = 0; ci < 32; ++ci) {
    int c = cg * 32 + ci;
    float val = bf2f(winb[(w >> 2) * 552 + (w & 3) * 136 + (c >> 5) * 34 + (c & 31)])
              + bf2f(lep[w * 130 + c]);
    out0[((size_t)(b * 128 + c) * 64 + h) * 64 + w] = val;
  }
}

extern "C" void kernel_launch(void* const* d_in, const int* in_sizes, int n_in,
                              void* d_out, int out_size, void* d_ws, size_t ws_size,
                              hipStream_t stream) {
  const float* x    = (const float*)d_in[0];
  const float* ai   = (const float*)d_in[1];
  const float* wq   = (const float*)d_in[2];
  const float* bq   = (const float*)d_in[3];
  const float* wv   = (const float*)d_in[4];
  const float* bv   = (const float*)d_in[5];
  const float* wl5  = (const float*)d_in[6];
  const float* bl   = (const float*)d_in[7];
  const float* temp = (const float*)d_in[8];
  float* out0 = (float*)d_out;
  float* attn = out0 + 8388608;

  char* ws = (char*)d_ws;
  unsigned short* xT = (unsigned short*)(ws);                 // 16 MB bf16 (raw x)
  unsigned short* qT = (unsigned short*)(ws + 16777216);      // 16 MB bf16 (raw q_map)
  unsigned short* vT = (unsigned short*)(ws + 33554432);      // 16 MB bf16
  unsigned short* lepe = (unsigned short*)(ws + 50331648);    // 16 MB bf16 NHWC
  unsigned short* ow = (unsigned short*)(ws + 83886080);      // 16 MB bf16 windowed

  k01_qv <<<dim3(32, 16),    256, 0, stream>>>(x, wq, bq, wv, bv, xT, qT, vT);
  k2_lepe<<<dim3(16, 4, 16), 256, 0, stream>>>(vT, wl5, bl, lepe);
  k3_attn<<<dim3(256, 4),    256, 0, stream>>>(xT, qT, vT, lepe, ai, temp, attn, ow);
  k4_out <<<dim3(64, 16),    256, 0, stream>>>(ow, lepe, out0);
}